// Round 15
// baseline (3048.403 us; speedup 1.0000x reference)
//
#include <hip/hip_runtime.h>
#include <hip/hip_bf16.h>

// Sizes (fixed by the problem)
#define BATCH 128
#define SEQ   512
#define IND   512
#define FSD   128
#define HS    512
#define G4    (4 * HS)   // 2048
#define G2    (2 * HS)   // 1024

// rec partitioning: 8 groups x 32 blocks; block = one 16-col slice, 4 gates
#define NG 8    // batch groups
#define GB 16   // batches per group
#define NS 32   // hidden slices (blocks per group)
#define SJ 16   // hidden per slice

typedef short short8_t __attribute__((ext_vector_type(8)));
typedef float f32x4 __attribute__((ext_vector_type(4)));

static __device__ __forceinline__ unsigned short f2bf(float f) {
    unsigned int u = __float_as_uint(f);
    unsigned int r = (u + 0x7fffu + ((u >> 16) & 1u)) >> 16;
    return (unsigned short)r;
}
static __device__ __forceinline__ float bf2f(unsigned short b) {
    return __uint_as_float(((unsigned int)b) << 16);
}
static __device__ __forceinline__ float sigmoidf_(float x) {
    return 1.0f / (1.0f + __expf(-x));
}

// ---------------------------------------------------------------------------
// Kernel 1: permute U_f [512][2048] f32 -> Up bf16 in MFMA B-fragment order.
// Up[(((s*4+g)*16+kt)*64+l)*8+i] = U_f[kt*32+(l>>4)*8+i][g*512+s*16+(l&15)]
// ---------------------------------------------------------------------------
__global__ __launch_bounds__(256)
void uconv_kernel(const float* __restrict__ Uf, unsigned short* __restrict__ Up) {
    int idx = blockIdx.x * 256 + threadIdx.x;   // 0 .. 2^20-1
    int i  = idx & 7;
    int l  = (idx >> 3) & 63;
    int kt = (idx >> 9) & 15;
    int g  = (idx >> 13) & 3;
    int s  = idx >> 15;
    int k  = kt * 32 + ((l >> 4) << 3) + i;
    int col = g * 512 + s * 16 + (l & 15);
    Up[idx] = f2bf(Uf[(size_t)k * G4 + col]);
}

// ---------------------------------------------------------------------------
// Kernel 1b: transpose+convert W_f [512][2048] f32 -> WfT [2048][512] bf16
// ---------------------------------------------------------------------------
__global__ __launch_bounds__(256)
void wtconv_kernel(const float* __restrict__ Wf, unsigned short* __restrict__ WfT) {
    __shared__ float tile[64][65];
    int k0 = blockIdx.x * 64;
    int n0 = blockIdx.y * 64;
    int tid = threadIdx.x;
    int r = tid >> 6, c = tid & 63;
    #pragma unroll
    for (int i = 0; i < 16; ++i)
        tile[r + 4 * i][c] = Wf[(size_t)(k0 + r + 4 * i) * G4 + n0 + c];
    __syncthreads();
    #pragma unroll
    for (int i = 0; i < 16; ++i)
        WfT[(size_t)(n0 + r + 4 * i) * IND + k0 + c] = f2bf(tile[c][r + 4 * i]);
}

// ---------------------------------------------------------------------------
// Kernel 1c: transpose+convert Wz [128][1024] f32 -> WzT [1024][128] bf16
// ---------------------------------------------------------------------------
__global__ __launch_bounds__(256)
void wzconv_kernel(const float* __restrict__ Wz, unsigned short* __restrict__ WzT) {
    __shared__ float tile[64][65];
    int k0 = blockIdx.x * 64;
    int n0 = blockIdx.y * 64;
    int tid = threadIdx.x;
    int r = tid >> 6, c = tid & 63;
    #pragma unroll
    for (int i = 0; i < 16; ++i)
        tile[r + 4 * i][c] = Wz[(size_t)(k0 + r + 4 * i) * G2 + n0 + c];
    __syncthreads();
    #pragma unroll
    for (int i = 0; i < 16; ++i)
        WzT[(size_t)(n0 + r + 4 * i) * FSD + k0 + c] = f2bf(tile[c][r + 4 * i]);
}

// ---------------------------------------------------------------------------
// Kernel 2: lz via MFMA (proven round 11).
// ---------------------------------------------------------------------------
__global__ __launch_bounds__(256)
void lzmm_kernel(const float* __restrict__ field, const unsigned short* __restrict__ WzT,
                 const float* __restrict__ biasz, unsigned short* __restrict__ lzOut) {
    __shared__ unsigned short As[128 * 64];
    __shared__ unsigned short Bs[128 * 64];
    int tid = threadIdx.x;
    int l = tid & 63, w = tid >> 6;
    int wr = w >> 1, wc = w & 1;
    int row0 = blockIdx.x * 128;
    int j0 = blockIdx.y * 64;

    f32x4 acc[4][4];
    #pragma unroll
    for (int m = 0; m < 4; ++m)
        #pragma unroll
        for (int n = 0; n < 4; ++n)
            acc[m][n] = (f32x4){0.f, 0.f, 0.f, 0.f};

    for (int k0 = 0; k0 < FSD; k0 += 64) {
        float4 av[4][2];
        short8_t bv[4];
        #pragma unroll
        for (int i = 0; i < 4; ++i) {
            int cidx = tid + 256 * i;
            int ar = cidx >> 3, sub = cidx & 7;
            int grow = row0 + ar;
            int b_ = grow & 127, s_ = grow >> 7;
            const float* ap = field + ((size_t)b_ * SEQ + s_) * FSD + k0 + sub * 8;
            av[i][0] = *(const float4*)ap;
            av[i][1] = *(const float4*)(ap + 4);
            int wzcol = ((ar >> 4) & 1) * HS + j0 + (((ar >> 5) << 4) | (ar & 15));
            bv[i] = *(const short8_t*)(WzT + (size_t)wzcol * FSD + k0 + sub * 8);
        }
        __syncthreads();
        #pragma unroll
        for (int i = 0; i < 4; ++i) {
            int cidx = tid + 256 * i;
            int ar = cidx >> 3, sub = cidx & 7;
            int off = ar * 64 + ((sub ^ (ar & 7)) << 3);
            short8_t a8;
            a8[0] = (short)f2bf(av[i][0].x); a8[1] = (short)f2bf(av[i][0].y);
            a8[2] = (short)f2bf(av[i][0].z); a8[3] = (short)f2bf(av[i][0].w);
            a8[4] = (short)f2bf(av[i][1].x); a8[5] = (short)f2bf(av[i][1].y);
            a8[6] = (short)f2bf(av[i][1].z); a8[7] = (short)f2bf(av[i][1].w);
            *(short8_t*)&As[off] = a8;
            *(short8_t*)&Bs[off] = bv[i];
        }
        __syncthreads();
        #pragma unroll
        for (int kt = 0; kt < 2; ++kt) {
            short8_t af[4], bfr[4];
            #pragma unroll
            for (int m = 0; m < 4; ++m) {
                int r = wr * 64 + m * 16 + (l & 15);
                int sub = kt * 4 + (l >> 4);
                af[m] = *(const short8_t*)&As[r * 64 + ((sub ^ (r & 7)) << 3)];
                int cc = wc * 64 + m * 16 + (l & 15);
                bfr[m] = *(const short8_t*)&Bs[cc * 64 + ((sub ^ (cc & 7)) << 3)];
            }
            #pragma unroll
            for (int m = 0; m < 4; ++m)
                #pragma unroll
                for (int n = 0; n < 4; ++n)
                    acc[m][n] = __builtin_amdgcn_mfma_f32_16x16x32_bf16(
                        af[m], bfr[n], acc[m][n], 0, 0, 0);
        }
        __syncthreads();
    }
    #pragma unroll
    for (int m = 0; m < 4; ++m) {
        int grow = row0 + wr * 64 + m * 16 + (l >> 4) * 4;
        #pragma unroll
        for (int q = 0; q < 2; ++q) {
            int j = j0 + (wc * 2 + q) * 16 + (l & 15);
            float bl = biasz[j];
            float bz = biasz[HS + j];
            f32x4 al = acc[m][2 * q];
            f32x4 az = acc[m][2 * q + 1];
            #pragma unroll
            for (int r = 0; r < 4; ++r) {
                float lv = sigmoidf_(al[r] + bl);
                float zv = tanhf(az[r] + bz);
                lzOut[(size_t)(grow + r) * HS + j] = f2bf(lv * zv);
            }
        }
    }
}

// ---------------------------------------------------------------------------
// Kernel 3: x_proj MFMA GEMM (proven) + XCD-locality block swizzle.
// ---------------------------------------------------------------------------
#define XBM 128
#define XBN 128
#define XBK 64
__global__ __launch_bounds__(256)
void xmm_kernel(const float* __restrict__ word, const unsigned short* __restrict__ WfT,
                const float* __restrict__ bias, unsigned short* __restrict__ xp) {
    __shared__ unsigned short As[XBM * XBK];
    __shared__ unsigned short Bs[XBN * XBK];
    int tid = threadIdx.x;
    int l = tid & 63, w = tid >> 6;
    int wr = w >> 1, wc = w & 1;
    int lin = blockIdx.x;
    int xcd = lin & 7;
    int idx = lin >> 3;
    int col0 = (idx & 15) * XBN;
    int row0 = (xcd * 64 + (idx >> 4)) * XBM;

    f32x4 acc[4][4];
    #pragma unroll
    for (int m = 0; m < 4; ++m)
        #pragma unroll
        for (int n = 0; n < 4; ++n)
            acc[m][n] = (f32x4){0.f, 0.f, 0.f, 0.f};

    for (int k0 = 0; k0 < IND; k0 += XBK) {
        float4 av[4][2];
        short8_t bv[4];
        #pragma unroll
        for (int i = 0; i < 4; ++i) {
            int c = tid + 256 * i;
            int ar = c >> 3, sub = c & 7;
            int grow = row0 + ar;
            int b_ = grow & 127, s_ = grow >> 7;
            const float* ap = word + ((size_t)b_ * SEQ + s_) * IND + k0 + sub * 8;
            av[i][0] = *(const float4*)ap;
            av[i][1] = *(const float4*)(ap + 4);
            bv[i] = *(const short8_t*)(WfT + (size_t)(col0 + ar) * IND + k0 + sub * 8);
        }
        __syncthreads();
        #pragma unroll
        for (int i = 0; i < 4; ++i) {
            int c = tid + 256 * i;
            int ar = c >> 3, sub = c & 7;
            int off = ar * 64 + ((sub ^ (ar & 7)) << 3);
            short8_t a8;
            a8[0] = (short)f2bf(av[i][0].x); a8[1] = (short)f2bf(av[i][0].y);
            a8[2] = (short)f2bf(av[i][0].z); a8[3] = (short)f2bf(av[i][0].w);
            a8[4] = (short)f2bf(av[i][1].x); a8[5] = (short)f2bf(av[i][1].y);
            a8[6] = (short)f2bf(av[i][1].z); a8[7] = (short)f2bf(av[i][1].w);
            *(short8_t*)&As[off] = a8;
            *(short8_t*)&Bs[off] = bv[i];
        }
        __syncthreads();
        #pragma unroll
        for (int kt = 0; kt < 2; ++kt) {
            short8_t af[4], bfr[4];
            #pragma unroll
            for (int m = 0; m < 4; ++m) {
                int r = wr * 64 + m * 16 + (l & 15);
                int sub = kt * 4 + (l >> 4);
                af[m] = *(const short8_t*)&As[r * 64 + ((sub ^ (r & 7)) << 3)];
                int cc = wc * 64 + m * 16 + (l & 15);
                bfr[m] = *(const short8_t*)&Bs[cc * 64 + ((sub ^ (cc & 7)) << 3)];
            }
            #pragma unroll
            for (int m = 0; m < 4; ++m)
                #pragma unroll
                for (int n = 0; n < 4; ++n)
                    acc[m][n] = __builtin_amdgcn_mfma_f32_16x16x32_bf16(
                        af[m], bfr[n], acc[m][n], 0, 0, 0);
        }
    }
    #pragma unroll
    for (int m = 0; m < 4; ++m) {
        int grow = row0 + wr * 64 + m * 16 + (l >> 4) * 4;
        #pragma unroll
        for (int n = 0; n < 4; ++n) {
            int gcol = col0 + wc * 64 + n * 16 + (l & 15);
            float bsv = bias[gcol];
            #pragma unroll
            for (int r = 0; r < 4; ++r)
                xp[(size_t)(grow + r) * G4 + gcol] = f2bf(acc[m][n][r] + bsv);
        }
    }
}

// ---------------------------------------------------------------------------
// Kernel 4: recurrence = rec12 (wave0-dedup poll + A->LDS) with PER-WAVE
// FLAGS: each wave publishes its own flag after draining its own h-stores,
// removing the trailing __syncthreads (2 barriers/step instead of 3).
// Ordering: wave flag(t) follows B2(t) -> follows that wave's ha_lds/gbuf
// reads, so observing all 128 group flags(t) licenses slot reuse exactly as
// rec12's single flag did.
// ---------------------------------------------------------------------------
__global__ __launch_bounds__(256, 1)
void rec15_kernel(const unsigned short* __restrict__ xp,
                  const unsigned short* __restrict__ lz,
                  const unsigned short* __restrict__ Up,
                  float* __restrict__ out,
                  unsigned short* __restrict__ hbuf,
                  unsigned int* __restrict__ flags) {
    const size_t HSEQ = (size_t)BATCH * SEQ * HS;
    const int HBG = GB * HS;   // 8192 ushorts per (slot, group)

    int bid = blockIdx.x;
    int g = bid & 7;
    int s = bid >> 3;          // 0..31
    int tid = threadIdx.x;
    int w = tid >> 6;          // gate
    int l = tid & 63;

    // U fragments staged once into LDS: [gate][kt][lane] 16B each = 64KB.
    __shared__ short8_t Ubs[4][16][64];
    {
        const short8_t* upw = (const short8_t*)(Up + ((size_t)(s * 4 + w) * 16) * 512);
        #pragma unroll
        for (int kt = 0; kt < 16; ++kt)
            Ubs[w][kt][l] = upw[kt * 64 + l];
    }
    __shared__ short8_t ha_lds[16][64];   // A fragments, 16KB, loaded by wave0
    __shared__ float gbuf[4][16][18];     // <=2-way (free) bank pattern
    __syncthreads();

    int eb = tid >> 4;            // batch-local 0..15
    int ej = tid & 15;            // col-local 0..15
    int jg = s * SJ + ej;         // global hidden col
    int bg = g * GB + eb;         // global batch
    int widx = (((jg >> 5) * 64 + eb + (((jg >> 3) & 3) << 4)) << 3) + (jg & 7);

    // per-wave flags: flags[g][slot][s][w], 128 u32 per (g, slot)
    unsigned int* fl = flags + (size_t)g * 2 * NS * 4;

    float c = 0.f, h_last = 0.f;

    for (int t = 0; t < SEQ; ++t) {
        size_t xb = ((size_t)t * BATCH + bg) * G4;
        float pgi = bf2f(xp[xb + jg]);
        float pgf = bf2f(xp[xb + HS + jg]);
        float pgg = bf2f(xp[xb + 2 * HS + jg]);
        float pgo = bf2f(xp[xb + 3 * HS + jg]);
        float plz = bf2f(lz[((size_t)t * BATCH + bg) * HS + jg]);

        f32x4 acc0 = {0.f, 0.f, 0.f, 0.f};
        f32x4 acc1 = {0.f, 0.f, 0.f, 0.f};
        if (t > 0) {
            if (w == 0) {
                // wave-0-only poll of the 128 per-wave flags of step t-1
                const unsigned int* fb = fl + ((t - 1) & 1) * NS * 4;
                const unsigned int* fp0 = fb + l;
                const unsigned int* fp1 = fb + 64 + l;
                int spins = 0;
                unsigned v0, v1;
                do {
                    v0 = __hip_atomic_load(fp0, __ATOMIC_RELAXED,
                                           __HIP_MEMORY_SCOPE_AGENT);
                    v1 = __hip_atomic_load(fp1, __ATOMIC_RELAXED,
                                           __HIP_MEMORY_SCOPE_AGENT);
                    if (++spins > (1 << 20)) break;
                } while (!__all((v0 == (unsigned)t) & (v1 == (unsigned)t)));

                // wave-0-only coherent A-fragment loads -> regs -> LDS
                const unsigned long long* ha64 = (const unsigned long long*)
                    (hbuf + (size_t)(((t - 1) & 1) * NG + g) * HBG);
                unsigned long long A2a[16], A2b[16];
                #pragma unroll
                for (int kt = 0; kt < 16; ++kt) {
                    int i0 = (kt * 64 + l) * 2;
                    A2a[kt] = __hip_atomic_load(&ha64[i0], __ATOMIC_RELAXED,
                                                __HIP_MEMORY_SCOPE_AGENT);
                    A2b[kt] = __hip_atomic_load(&ha64[i0 + 1], __ATOMIC_RELAXED,
                                                __HIP_MEMORY_SCOPE_AGENT);
                }
                #pragma unroll
                for (int kt = 0; kt < 16; ++kt) {
                    union { unsigned long long u[2]; short8_t v8; } A;
                    A.u[0] = A2a[kt]; A.u[1] = A2b[kt];
                    ha_lds[kt][l] = A.v8;
                }
            }
            __syncthreads();   // B1: h_t-1 fragments visible in LDS

            #pragma unroll
            for (int kt = 0; kt < 16; ++kt) {
                short8_t av = ha_lds[kt][l];
                short8_t bf = Ubs[w][kt][l];
                if (kt & 1)
                    acc1 = __builtin_amdgcn_mfma_f32_16x16x32_bf16(av, bf, acc1, 0, 0, 0);
                else
                    acc0 = __builtin_amdgcn_mfma_f32_16x16x32_bf16(av, bf, acc0, 0, 0, 0);
            }
            acc0 += acc1;
        }
        #pragma unroll
        for (int r = 0; r < 4; ++r)
            gbuf[w][(l >> 4) * 4 + r][l & 15] = acc0[r];
        __syncthreads();   // B2: gbuf ready for epilogue

        float gi = gbuf[0][eb][ej] + pgi;
        float gf = gbuf[1][eb][ej] + pgf;
        float gg = gbuf[2][eb][ej] + pgg;
        float go = gbuf[3][eb][ej] + pgo;
        float i_ = sigmoidf_(gi);
        float f_ = sigmoidf_(gf + 1.0f);
        float g_ = tanhf(gg);
        float o_ = sigmoidf_(go);
        c = f_ * c + i_ * g_ + plz;
        float h = o_ * tanhf(c);
        h_last = h;

        unsigned short hv = f2bf(h);
        unsigned partner = (unsigned)(unsigned short)__shfl_down((int)hv, 1);
        if ((ej & 1) == 0) {
            unsigned int* hb32 = (unsigned int*)
                (hbuf + (size_t)((t & 1) * NG + g) * HBG);
            __hip_atomic_store(&hb32[widx >> 1], (unsigned)hv | (partner << 16),
                               __ATOMIC_RELAXED, __HIP_MEMORY_SCOPE_AGENT);
        }
        // per-wave drain + per-wave flag (no trailing barrier)
        asm volatile("s_waitcnt vmcnt(0)" ::: "memory");
        if (l == 0)
            __hip_atomic_store(&fl[(t & 1) * NS * 4 + s * 4 + w],
                               (unsigned)(t + 1),
                               __ATOMIC_RELAXED, __HIP_MEMORY_SCOPE_AGENT);

        // hidden-seq output AFTER flag publication (off the critical path)
        out[((size_t)bg * SEQ + t) * HS + jg] = h;
    }

    out[HSEQ + (size_t)bg * HS + jg] = h_last;
    out[HSEQ + (size_t)BATCH * HS + (size_t)bg * HS + jg] = c;
}

// ---------------------------------------------------------------------------
extern "C" void kernel_launch(void* const* d_in, const int* in_sizes, int n_in,
                              void* d_out, int out_size, void* d_ws, size_t ws_size,
                              hipStream_t stream) {
    const float* word   = (const float*)d_in[0];
    const float* field  = (const float*)d_in[1];
    const float* Wf     = (const float*)d_in[2];
    const float* Wz     = (const float*)d_in[3];
    const float* Uf     = (const float*)d_in[4];
    const float* bias_f = (const float*)d_in[5];
    const float* biasz  = (const float*)d_in[6];
    float* out = (float*)d_out;

    // Workspace:
    //   xp   : bf16 [S][B][4H] = 268,435,456
    //   lz   : bf16 [S][B][H]  =  67,108,864
    //   Up   : bf16 frag-order =   2,097,152
    //   WfT  : bf16 [N][K]     =   2,097,152
    //   WzT  : bf16 [N][K]     =     262,144
    //   hbuf : bf16 2x8x8192   =     262,144
    //   flags: u32 8x2x32x4    =       8,192
    char* p = (char*)d_ws;
    unsigned short* xp   = (unsigned short*)p;  p += (size_t)SEQ * BATCH * G4 * 2;
    unsigned short* lzb  = (unsigned short*)p;  p += (size_t)SEQ * BATCH * HS * 2;
    unsigned short* Up   = (unsigned short*)p;  p += (size_t)IND * G4 * 2;
    unsigned short* WfT  = (unsigned short*)p;  p += (size_t)G4 * IND * 2;
    unsigned short* WzT  = (unsigned short*)p;  p += (size_t)G2 * FSD * 2;
    unsigned short* hbuf = (unsigned short*)p;  p += (size_t)2 * NG * GB * HS * 2;
    unsigned int*   flags= (unsigned int*)p;    p += (size_t)NG * 2 * NS * 4 * 4;

    // clear flags (harness does NOT re-poison ws between graph replays)
    hipMemsetAsync(flags, 0, (size_t)NG * 2 * NS * 4 * 4, stream);

    uconv_kernel<<<(IND * G4) / 256, 256, 0, stream>>>(Uf, Up);

    dim3 gt(IND / 64, G4 / 64);
    wtconv_kernel<<<gt, 256, 0, stream>>>(Wf, WfT);

    dim3 gz(FSD / 64, G2 / 64);
    wzconv_kernel<<<gz, 256, 0, stream>>>(Wz, WzT);

    dim3 glz((SEQ * BATCH) / 128, HS / 64);
    lzmm_kernel<<<glz, 256, 0, stream>>>(field, WzT, biasz, lzb);

    xmm_kernel<<<(SEQ * BATCH / XBM) * (G4 / XBN), 256, 0, stream>>>(
        word, WfT, bias_f, xp);

    rec15_kernel<<<NG * NS, 256, 0, stream>>>(xp, lzb, Up, out, hbuf, flags);
}

// Round 16
// 1767.088 us; speedup vs baseline: 1.7251x; 1.7251x over previous
//
#include <hip/hip_runtime.h>
#include <hip/hip_bf16.h>

// Sizes (fixed by the problem)
#define BATCH 128
#define SEQ   512
#define IND   512
#define FSD   128
#define HS    512
#define G4    (4 * HS)   // 2048
#define G2    (2 * HS)   // 1024

// rec partitioning: 8 groups x 32 blocks; block = one 16-col slice, 4 gates
#define NG 8    // batch groups
#define GB 16   // batches per group
#define NS 32   // hidden slices (blocks per group)
#define SJ 16   // hidden per slice

typedef short short8_t __attribute__((ext_vector_type(8)));
typedef float f32x4 __attribute__((ext_vector_type(4)));

static __device__ __forceinline__ unsigned short f2bf(float f) {
    unsigned int u = __float_as_uint(f);
    unsigned int r = (u + 0x7fffu + ((u >> 16) & 1u)) >> 16;
    return (unsigned short)r;
}
static __device__ __forceinline__ float bf2f(unsigned short b) {
    return __uint_as_float(((unsigned int)b) << 16);
}
static __device__ __forceinline__ float sigmoidf_(float x) {
    return 1.0f / (1.0f + __expf(-x));
}

// ---------------------------------------------------------------------------
// Kernel 1: permute U_f [512][2048] f32 -> Up bf16 in MFMA B-fragment order.
// Up[(((s*4+g)*16+kt)*64+l)*8+i] = U_f[kt*32+(l>>4)*8+i][g*512+s*16+(l&15)]
// ---------------------------------------------------------------------------
__global__ __launch_bounds__(256)
void uconv_kernel(const float* __restrict__ Uf, unsigned short* __restrict__ Up) {
    int idx = blockIdx.x * 256 + threadIdx.x;   // 0 .. 2^20-1
    int i  = idx & 7;
    int l  = (idx >> 3) & 63;
    int kt = (idx >> 9) & 15;
    int g  = (idx >> 13) & 3;
    int s  = idx >> 15;
    int k  = kt * 32 + ((l >> 4) << 3) + i;
    int col = g * 512 + s * 16 + (l & 15);
    Up[idx] = f2bf(Uf[(size_t)k * G4 + col]);
}

// ---------------------------------------------------------------------------
// Kernel 1b: transpose+convert W_f [512][2048] f32 -> WfT [2048][512] bf16
// ---------------------------------------------------------------------------
__global__ __launch_bounds__(256)
void wtconv_kernel(const float* __restrict__ Wf, unsigned short* __restrict__ WfT) {
    __shared__ float tile[64][65];
    int k0 = blockIdx.x * 64;
    int n0 = blockIdx.y * 64;
    int tid = threadIdx.x;
    int r = tid >> 6, c = tid & 63;
    #pragma unroll
    for (int i = 0; i < 16; ++i)
        tile[r + 4 * i][c] = Wf[(size_t)(k0 + r + 4 * i) * G4 + n0 + c];
    __syncthreads();
    #pragma unroll
    for (int i = 0; i < 16; ++i)
        WfT[(size_t)(n0 + r + 4 * i) * IND + k0 + c] = f2bf(tile[c][r + 4 * i]);
}

// ---------------------------------------------------------------------------
// Kernel 1c: transpose+convert Wz [128][1024] f32 -> WzT [1024][128] bf16
// ---------------------------------------------------------------------------
__global__ __launch_bounds__(256)
void wzconv_kernel(const float* __restrict__ Wz, unsigned short* __restrict__ WzT) {
    __shared__ float tile[64][65];
    int k0 = blockIdx.x * 64;
    int n0 = blockIdx.y * 64;
    int tid = threadIdx.x;
    int r = tid >> 6, c = tid & 63;
    #pragma unroll
    for (int i = 0; i < 16; ++i)
        tile[r + 4 * i][c] = Wz[(size_t)(k0 + r + 4 * i) * G2 + n0 + c];
    __syncthreads();
    #pragma unroll
    for (int i = 0; i < 16; ++i)
        WzT[(size_t)(n0 + r + 4 * i) * FSD + k0 + c] = f2bf(tile[c][r + 4 * i]);
}

// ---------------------------------------------------------------------------
// Kernel 2: lz via MFMA (proven round 11). K=128, gate-interleaved B cols,
// fused sigmoid*tanh epilogue. Output lz[s][b][j] bf16.
// ---------------------------------------------------------------------------
__global__ __launch_bounds__(256)
void lzmm_kernel(const float* __restrict__ field, const unsigned short* __restrict__ WzT,
                 const float* __restrict__ biasz, unsigned short* __restrict__ lzOut) {
    __shared__ unsigned short As[128 * 64];
    __shared__ unsigned short Bs[128 * 64];
    int tid = threadIdx.x;
    int l = tid & 63, w = tid >> 6;
    int wr = w >> 1, wc = w & 1;
    int row0 = blockIdx.x * 128;
    int j0 = blockIdx.y * 64;

    f32x4 acc[4][4];
    #pragma unroll
    for (int m = 0; m < 4; ++m)
        #pragma unroll
        for (int n = 0; n < 4; ++n)
            acc[m][n] = (f32x4){0.f, 0.f, 0.f, 0.f};

    for (int k0 = 0; k0 < FSD; k0 += 64) {
        float4 av[4][2];
        short8_t bv[4];
        #pragma unroll
        for (int i = 0; i < 4; ++i) {
            int cidx = tid + 256 * i;
            int ar = cidx >> 3, sub = cidx & 7;
            int grow = row0 + ar;
            int b_ = grow & 127, s_ = grow >> 7;
            const float* ap = field + ((size_t)b_ * SEQ + s_) * FSD + k0 + sub * 8;
            av[i][0] = *(const float4*)ap;
            av[i][1] = *(const float4*)(ap + 4);
            int wzcol = ((ar >> 4) & 1) * HS + j0 + (((ar >> 5) << 4) | (ar & 15));
            bv[i] = *(const short8_t*)(WzT + (size_t)wzcol * FSD + k0 + sub * 8);
        }
        __syncthreads();
        #pragma unroll
        for (int i = 0; i < 4; ++i) {
            int cidx = tid + 256 * i;
            int ar = cidx >> 3, sub = cidx & 7;
            int off = ar * 64 + ((sub ^ (ar & 7)) << 3);
            short8_t a8;
            a8[0] = (short)f2bf(av[i][0].x); a8[1] = (short)f2bf(av[i][0].y);
            a8[2] = (short)f2bf(av[i][0].z); a8[3] = (short)f2bf(av[i][0].w);
            a8[4] = (short)f2bf(av[i][1].x); a8[5] = (short)f2bf(av[i][1].y);
            a8[6] = (short)f2bf(av[i][1].z); a8[7] = (short)f2bf(av[i][1].w);
            *(short8_t*)&As[off] = a8;
            *(short8_t*)&Bs[off] = bv[i];
        }
        __syncthreads();
        #pragma unroll
        for (int kt = 0; kt < 2; ++kt) {
            short8_t af[4], bfr[4];
            #pragma unroll
            for (int m = 0; m < 4; ++m) {
                int r = wr * 64 + m * 16 + (l & 15);
                int sub = kt * 4 + (l >> 4);
                af[m] = *(const short8_t*)&As[r * 64 + ((sub ^ (r & 7)) << 3)];
                int cc = wc * 64 + m * 16 + (l & 15);
                bfr[m] = *(const short8_t*)&Bs[cc * 64 + ((sub ^ (cc & 7)) << 3)];
            }
            #pragma unroll
            for (int m = 0; m < 4; ++m)
                #pragma unroll
                for (int n = 0; n < 4; ++n)
                    acc[m][n] = __builtin_amdgcn_mfma_f32_16x16x32_bf16(
                        af[m], bfr[n], acc[m][n], 0, 0, 0);
        }
        __syncthreads();
    }
    #pragma unroll
    for (int m = 0; m < 4; ++m) {
        int grow = row0 + wr * 64 + m * 16 + (l >> 4) * 4;
        #pragma unroll
        for (int q = 0; q < 2; ++q) {
            int j = j0 + (wc * 2 + q) * 16 + (l & 15);
            float bl = biasz[j];
            float bz = biasz[HS + j];
            f32x4 al = acc[m][2 * q];
            f32x4 az = acc[m][2 * q + 1];
            #pragma unroll
            for (int r = 0; r < 4; ++r) {
                float lv = sigmoidf_(al[r] + bl);
                float zv = tanhf(az[r] + bz);
                lzOut[(size_t)(grow + r) * HS + j] = f2bf(lv * zv);
            }
        }
    }
}

// ---------------------------------------------------------------------------
// Kernel 3: x_proj MFMA GEMM (proven) + XCD-locality block swizzle:
// the 16 col-blocks sharing one A-panel run consecutively on one XCD
// (A-panel L2-reuse x16; B = 2MB stays L2-resident). 1D grid of 8192.
// ---------------------------------------------------------------------------
#define XBM 128
#define XBN 128
#define XBK 64
__global__ __launch_bounds__(256)
void xmm_kernel(const float* __restrict__ word, const unsigned short* __restrict__ WfT,
                const float* __restrict__ bias, unsigned short* __restrict__ xp) {
    __shared__ unsigned short As[XBM * XBK];
    __shared__ unsigned short Bs[XBN * XBK];
    int tid = threadIdx.x;
    int l = tid & 63, w = tid >> 6;
    int wr = w >> 1, wc = w & 1;
    int lin = blockIdx.x;
    int xcd = lin & 7;
    int idx = lin >> 3;                       // 0..1023
    int col0 = (idx & 15) * XBN;
    int row0 = (xcd * 64 + (idx >> 4)) * XBM;

    f32x4 acc[4][4];
    #pragma unroll
    for (int m = 0; m < 4; ++m)
        #pragma unroll
        for (int n = 0; n < 4; ++n)
            acc[m][n] = (f32x4){0.f, 0.f, 0.f, 0.f};

    for (int k0 = 0; k0 < IND; k0 += XBK) {
        float4 av[4][2];
        short8_t bv[4];
        #pragma unroll
        for (int i = 0; i < 4; ++i) {
            int c = tid + 256 * i;
            int ar = c >> 3, sub = c & 7;
            int grow = row0 + ar;
            int b_ = grow & 127, s_ = grow >> 7;
            const float* ap = word + ((size_t)b_ * SEQ + s_) * IND + k0 + sub * 8;
            av[i][0] = *(const float4*)ap;
            av[i][1] = *(const float4*)(ap + 4);
            bv[i] = *(const short8_t*)(WfT + (size_t)(col0 + ar) * IND + k0 + sub * 8);
        }
        __syncthreads();
        #pragma unroll
        for (int i = 0; i < 4; ++i) {
            int c = tid + 256 * i;
            int ar = c >> 3, sub = c & 7;
            int off = ar * 64 + ((sub ^ (ar & 7)) << 3);
            short8_t a8;
            a8[0] = (short)f2bf(av[i][0].x); a8[1] = (short)f2bf(av[i][0].y);
            a8[2] = (short)f2bf(av[i][0].z); a8[3] = (short)f2bf(av[i][0].w);
            a8[4] = (short)f2bf(av[i][1].x); a8[5] = (short)f2bf(av[i][1].y);
            a8[6] = (short)f2bf(av[i][1].z); a8[7] = (short)f2bf(av[i][1].w);
            *(short8_t*)&As[off] = a8;
            *(short8_t*)&Bs[off] = bv[i];
        }
        __syncthreads();
        #pragma unroll
        for (int kt = 0; kt < 2; ++kt) {
            short8_t af[4], bfr[4];
            #pragma unroll
            for (int m = 0; m < 4; ++m) {
                int r = wr * 64 + m * 16 + (l & 15);
                int sub = kt * 4 + (l >> 4);
                af[m] = *(const short8_t*)&As[r * 64 + ((sub ^ (r & 7)) << 3)];
                int cc = wc * 64 + m * 16 + (l & 15);
                bfr[m] = *(const short8_t*)&Bs[cc * 64 + ((sub ^ (cc & 7)) << 3)];
            }
            #pragma unroll
            for (int m = 0; m < 4; ++m)
                #pragma unroll
                for (int n = 0; n < 4; ++n)
                    acc[m][n] = __builtin_amdgcn_mfma_f32_16x16x32_bf16(
                        af[m], bfr[n], acc[m][n], 0, 0, 0);
        }
    }
    #pragma unroll
    for (int m = 0; m < 4; ++m) {
        int grow = row0 + wr * 64 + m * 16 + (l >> 4) * 4;
        #pragma unroll
        for (int n = 0; n < 4; ++n) {
            int gcol = col0 + wc * 64 + n * 16 + (l & 15);
            float bsv = bias[gcol];
            #pragma unroll
            for (int r = 0; r < 4; ++r)
                xp[(size_t)(grow + r) * G4 + gcol] = f2bf(acc[m][n][r] + bsv);
        }
    }
}

// ---------------------------------------------------------------------------
// Kernel 4: recurrence = rec7 protocol + WAVE-0 DEDUP of poll + A-loads.
// (Round-12 proven optimum: 1415 us.) Only wave 0 polls the flags and pulls
// the A-fragment set (coherent loads into regs, then LDS); waves 1-3 wait at
// a barrier and read A via ds_read_b128. Cuts per-step LLC requests 4x.
// Producer path: h-stores -> vmcnt drain -> barrier -> single per-block flag.
// ---------------------------------------------------------------------------
__global__ __launch_bounds__(256, 1)
void rec12_kernel(const unsigned short* __restrict__ xp,
                  const unsigned short* __restrict__ lz,
                  const unsigned short* __restrict__ Up,
                  float* __restrict__ out,
                  unsigned short* __restrict__ hbuf,
                  unsigned int* __restrict__ flags) {
    const size_t HSEQ = (size_t)BATCH * SEQ * HS;
    const int HBG = GB * HS;   // 8192 ushorts per (slot, group)

    int bid = blockIdx.x;
    int g = bid & 7;
    int s = bid >> 3;          // 0..31
    int tid = threadIdx.x;
    int w = tid >> 6;          // gate
    int l = tid & 63;

    // U fragments staged once into LDS: [gate][kt][lane] 16B each = 64KB.
    __shared__ short8_t Ubs[4][16][64];
    {
        const short8_t* upw = (const short8_t*)(Up + ((size_t)(s * 4 + w) * 16) * 512);
        #pragma unroll
        for (int kt = 0; kt < 16; ++kt)
            Ubs[w][kt][l] = upw[kt * 64 + l];
    }
    __shared__ short8_t ha_lds[16][64];   // A fragments, 16KB, loaded by wave0
    __shared__ float gbuf[4][16][18];     // <=2-way (free) bank pattern
    __syncthreads();

    int eb = tid >> 4;            // batch-local 0..15
    int ej = tid & 15;            // col-local 0..15
    int jg = s * SJ + ej;         // global hidden col
    int bg = g * GB + eb;         // global batch
    int widx = (((jg >> 5) * 64 + eb + (((jg >> 3) & 3) << 4)) << 3) + (jg & 7);

    unsigned int* fl = flags + (size_t)g * 2 * NS;

    float c = 0.f, h_last = 0.f;

    for (int t = 0; t < SEQ; ++t) {
        size_t xb = ((size_t)t * BATCH + bg) * G4;
        float pgi = bf2f(xp[xb + jg]);
        float pgf = bf2f(xp[xb + HS + jg]);
        float pgg = bf2f(xp[xb + 2 * HS + jg]);
        float pgo = bf2f(xp[xb + 3 * HS + jg]);
        float plz = bf2f(lz[((size_t)t * BATCH + bg) * HS + jg]);

        f32x4 acc0 = {0.f, 0.f, 0.f, 0.f};
        f32x4 acc1 = {0.f, 0.f, 0.f, 0.f};
        if (t > 0) {
            if (w == 0) {
                // wave-0-only poll of the 32 producer flags of step t-1
                const unsigned int* fp = fl + ((t - 1) & 1) * NS + (l & 31);
                int spins = 0;
                unsigned v;
                do {
                    v = __hip_atomic_load(fp, __ATOMIC_RELAXED,
                                          __HIP_MEMORY_SCOPE_AGENT);
                    if (++spins > (1 << 20)) break;
                } while (!__all(v == (unsigned)t));

                // wave-0-only coherent A-fragment loads -> regs -> LDS
                const unsigned long long* ha64 = (const unsigned long long*)
                    (hbuf + (size_t)(((t - 1) & 1) * NG + g) * HBG);
                unsigned long long A2a[16], A2b[16];
                #pragma unroll
                for (int kt = 0; kt < 16; ++kt) {
                    int i0 = (kt * 64 + l) * 2;
                    A2a[kt] = __hip_atomic_load(&ha64[i0], __ATOMIC_RELAXED,
                                                __HIP_MEMORY_SCOPE_AGENT);
                    A2b[kt] = __hip_atomic_load(&ha64[i0 + 1], __ATOMIC_RELAXED,
                                                __HIP_MEMORY_SCOPE_AGENT);
                }
                #pragma unroll
                for (int kt = 0; kt < 16; ++kt) {
                    union { unsigned long long u[2]; short8_t v8; } A;
                    A.u[0] = A2a[kt]; A.u[1] = A2b[kt];
                    ha_lds[kt][l] = A.v8;
                }
            }
            __syncthreads();   // h_t-1 fragments visible in LDS to all waves

            #pragma unroll
            for (int kt = 0; kt < 16; ++kt) {
                short8_t av = ha_lds[kt][l];
                short8_t bf = Ubs[w][kt][l];
                if (kt & 1)
                    acc1 = __builtin_amdgcn_mfma_f32_16x16x32_bf16(av, bf, acc1, 0, 0, 0);
                else
                    acc0 = __builtin_amdgcn_mfma_f32_16x16x32_bf16(av, bf, acc0, 0, 0, 0);
            }
            acc0 += acc1;
        }
        #pragma unroll
        for (int r = 0; r < 4; ++r)
            gbuf[w][(l >> 4) * 4 + r][l & 15] = acc0[r];
        __syncthreads();

        float gi = gbuf[0][eb][ej] + pgi;
        float gf = gbuf[1][eb][ej] + pgf;
        float gg = gbuf[2][eb][ej] + pgg;
        float go = gbuf[3][eb][ej] + pgo;
        float i_ = sigmoidf_(gi);
        float f_ = sigmoidf_(gf + 1.0f);
        float g_ = tanhf(gg);
        float o_ = sigmoidf_(go);
        c = f_ * c + i_ * g_ + plz;
        float h = o_ * tanhf(c);
        h_last = h;

        unsigned short hv = f2bf(h);
        unsigned partner = (unsigned)(unsigned short)__shfl_down((int)hv, 1);
        if ((ej & 1) == 0) {
            unsigned int* hb32 = (unsigned int*)
                (hbuf + (size_t)((t & 1) * NG + g) * HBG);
            __hip_atomic_store(&hb32[widx >> 1], (unsigned)hv | (partner << 16),
                               __ATOMIC_RELAXED, __HIP_MEMORY_SCOPE_AGENT);
        }
        asm volatile("s_waitcnt vmcnt(0)" ::: "memory");
        __syncthreads();   // all threads' h stores drained; gbuf reads done
        if (tid == 0)
            __hip_atomic_store(&fl[(t & 1) * NS + s], (unsigned)(t + 1),
                               __ATOMIC_RELAXED, __HIP_MEMORY_SCOPE_AGENT);

        out[((size_t)bg * SEQ + t) * HS + jg] = h;
    }

    out[HSEQ + (size_t)bg * HS + jg] = h_last;
    out[HSEQ + (size_t)BATCH * HS + (size_t)bg * HS + jg] = c;
}

// ---------------------------------------------------------------------------
extern "C" void kernel_launch(void* const* d_in, const int* in_sizes, int n_in,
                              void* d_out, int out_size, void* d_ws, size_t ws_size,
                              hipStream_t stream) {
    const float* word   = (const float*)d_in[0];
    const float* field  = (const float*)d_in[1];
    const float* Wf     = (const float*)d_in[2];
    const float* Wz     = (const float*)d_in[3];
    const float* Uf     = (const float*)d_in[4];
    const float* bias_f = (const float*)d_in[5];
    const float* biasz  = (const float*)d_in[6];
    float* out = (float*)d_out;

    // Workspace:
    //   xp   : bf16 [S][B][4H] = 268,435,456
    //   lz   : bf16 [S][B][H]  =  67,108,864
    //   Up   : bf16 frag-order =   2,097,152
    //   WfT  : bf16 [N][K]     =   2,097,152
    //   WzT  : bf16 [N][K]     =     262,144
    //   hbuf : bf16 2x8x8192   =     262,144
    //   flags: u32 8x2x32      =       2,048
    char* p = (char*)d_ws;
    unsigned short* xp   = (unsigned short*)p;  p += (size_t)SEQ * BATCH * G4 * 2;
    unsigned short* lzb  = (unsigned short*)p;  p += (size_t)SEQ * BATCH * HS * 2;
    unsigned short* Up   = (unsigned short*)p;  p += (size_t)IND * G4 * 2;
    unsigned short* WfT  = (unsigned short*)p;  p += (size_t)G4 * IND * 2;
    unsigned short* WzT  = (unsigned short*)p;  p += (size_t)G2 * FSD * 2;
    unsigned short* hbuf = (unsigned short*)p;  p += (size_t)2 * NG * GB * HS * 2;
    unsigned int*   flags= (unsigned int*)p;    p += (size_t)NG * 2 * NS * 4;

    // clear flags (harness does NOT re-poison ws between graph replays)
    hipMemsetAsync(flags, 0, (size_t)NG * 2 * NS * 4, stream);

    uconv_kernel<<<(IND * G4) / 256, 256, 0, stream>>>(Uf, Up);

    dim3 gt(IND / 64, G4 / 64);
    wtconv_kernel<<<gt, 256, 0, stream>>>(Wf, WfT);

    dim3 gz(FSD / 64, G2 / 64);
    wzconv_kernel<<<gz, 256, 0, stream>>>(Wz, WzT);

    dim3 glz((SEQ * BATCH) / 128, HS / 64);
    lzmm_kernel<<<glz, 256, 0, stream>>>(field, WzT, biasz, lzb);

    xmm_kernel<<<(SEQ * BATCH / XBM) * (G4 / XBN), 256, 0, stream>>>(
        word, WfT, bias_f, xp);

    rec12_kernel<<<NG * NS, 256, 0, stream>>>(xp, lzb, Up, out, hbuf, flags);
}